// Round 4
// baseline (211.521 us; speedup 1.0000x reference)
//
#include <hip/hip_runtime.h>
#include <hip/hip_bf16.h>
#include <stdint.h>

typedef short bf16x8 __attribute__((ext_vector_type(8)));
typedef float f32x4 __attribute__((ext_vector_type(4)));
typedef unsigned short u16;

// ---- helpers -------------------------------------------------------------

__device__ __forceinline__ u16 f2bf_bits(float f) {
    __hip_bfloat16 h = __float2bfloat16(f);
    return __builtin_bit_cast(u16, h);
}

// pack two floats to bf16 pair (round-half-up): low = a, high = b
__device__ __forceinline__ uint32_t pack2bf(float a, float b) {
    uint32_t ua = __builtin_bit_cast(uint32_t, a) + 0x8000u;
    uint32_t ub = __builtin_bit_cast(uint32_t, b) + 0x8000u;
    return __builtin_amdgcn_perm(ub, ua, 0x07060302u);
}

// async global->LDS, 16B per lane; LDS dest = wave-uniform base + lane*16
__device__ __forceinline__ void gld_lds16(const void* g, void* l) {
    __builtin_amdgcn_global_load_lds(
        (const __attribute__((address_space(1))) void*)g,
        (__attribute__((address_space(3))) void*)l, 16, 0, 0);
}

#define CEXP 0.18033688011112042f  // log2(e)/8 : exp(s/8) = exp2(s*CEXP)

// ---- fused cast kernel ---------------------------------------------------
// region A: x (1,572,864 float4) ; region B: wq|wk|wv|wo (589,824 float4)

__global__ __launch_bounds__(256) void cast_all_kernel(
    const float* __restrict__ x, const float* __restrict__ w0,
    const float* __restrict__ w1, const float* __restrict__ w2,
    const float* __restrict__ w3, u16* __restrict__ xb,
    u16* __restrict__ o0, u16* __restrict__ o1,
    u16* __restrict__ o2, u16* __restrict__ o3,
    const float* __restrict__ bq, const float* __restrict__ bk,
    const float* __restrict__ bv, float* __restrict__ biasf) {
    int gid = blockIdx.x * 256 + threadIdx.x;
    const float* s;
    u16* d;
    int off;
    if (gid < 1572864) {
        s = x; d = xb; off = gid;
    } else {
        int g2 = gid - 1572864;
        int which = g2 / 147456;
        off = g2 - which * 147456;
        s = which == 0 ? w0 : which == 1 ? w1 : which == 2 ? w2 : w3;
        d = which == 0 ? o0 : which == 1 ? o1 : which == 2 ? o2 : o3;
    }
    float4 v = ((const float4*)s)[off];
    ushort4 u;
    u.x = f2bf_bits(v.x); u.y = f2bf_bits(v.y);
    u.z = f2bf_bits(v.z); u.w = f2bf_bits(v.w);
    ((ushort4*)d)[off] = u;
    if (gid < 2304) {
        float bb = gid < 768 ? bq[gid] : gid < 1536 ? bk[gid - 768] : bv[gid - 1536];
        biasf[gid] = bb;
    }
}

// ---- GEMM: C[m,n] = sum_k X[m,k]*W[n,k] + bias[n]  (both row-major in K)
// BK=64, block tile RT x 128, 4 waves 2x2, wave tile (RT/2) x 64.
// LDS rows 128B = 8 chunks of 16B; slot(row,c) = c ^ ((row ^ (row>>3)) & 7)
// -> staging matches gld_lds16 lane order; frag ds_read_b128 is 2-way (free).
// MODE: 0 = bf16 out, 1 = f32 out, 2 = QKV fused (V n-tiles -> Vt transposed)

template <int RT, int MODE>
__global__ __launch_bounds__(256) void gemm_xwt(
    const u16* __restrict__ X, const u16* __restrict__ W,
    const float* __restrict__ bias, float* __restrict__ Cf,
    u16* __restrict__ Cb, u16* __restrict__ Vt, int K, int NC) {
    constexpr int JR = RT / 32;
    __shared__ u16 lsX[RT * 64];
    __shared__ u16 lsW[128 * 64];
    const int tid = threadIdx.x;
    const int w = tid >> 6, lane = tid & 63;
    const int quad = lane >> 4, l15 = lane & 15;
    const int m0 = blockIdx.y * RT, n0 = blockIdx.x * 128;
    const int wr = (w >> 1) * (RT / 2), wc = (w & 1) * 64;
    const int rr = lane >> 3, c8 = lane & 7;

    f32x4 acc[JR][4];
    for (int j = 0; j < JR; ++j)
        for (int i = 0; i < 4; ++i) acc[j][i] = (f32x4){0.f, 0.f, 0.f, 0.f};

    const int KT = K / 64;
    for (int kt = 0; kt < KT; ++kt) {
        const int k0 = kt * 64;
        __syncthreads();
        for (int cb = w; cb < RT / 8; cb += 4) {
            int row = cb * 8 + rr;
            int cg = c8 ^ ((rr ^ cb) & 7);
            gld_lds16(X + (size_t)(m0 + row) * K + k0 + cg * 8, &lsX[cb * 512]);
        }
        for (int cb = w; cb < 16; cb += 4) {
            int row = cb * 8 + rr;
            int cg = c8 ^ ((rr ^ cb) & 7);
            gld_lds16(W + (size_t)(n0 + row) * K + k0 + cg * 8, &lsW[cb * 512]);
        }
        __syncthreads();

        for (int kk = 0; kk < 2; ++kk) {
            bf16x8 xf[JR], wf[4];
            for (int j = 0; j < JR; ++j) {
                int row = wr + j * 16 + l15;
                int slot = (kk * 4 + quad) ^ ((row ^ (row >> 3)) & 7);
                xf[j] = *(const bf16x8*)&lsX[row * 64 + slot * 8];
            }
            for (int i = 0; i < 4; ++i) {
                int row = wc + i * 16 + l15;
                int slot = (kk * 4 + quad) ^ ((row ^ (row >> 3)) & 7);
                wf[i] = *(const bf16x8*)&lsW[row * 64 + slot * 8];
            }
            for (int j = 0; j < JR; ++j)
                for (int i = 0; i < 4; ++i)
                    acc[j][i] = __builtin_amdgcn_mfma_f32_16x16x32_bf16(
                        wf[i], xf[j], acc[j][i], 0, 0, 0);
        }
    }

    const bool vtile = (MODE == 2) && (n0 >= 1536);
    for (int i = 0; i < 4; ++i) {
        int c0 = n0 + wc + i * 16 + quad * 4;
        float4 bv4 = *(const float4*)&bias[c0];
        for (int j = 0; j < JR; ++j) {
            int row = m0 + wr + j * 16 + l15;
            float v0 = acc[j][i][0] + bv4.x;
            float v1 = acc[j][i][1] + bv4.y;
            float v2 = acc[j][i][2] + bv4.z;
            float v3 = acc[j][i][3] + bv4.w;
            if (MODE == 1) {
                float4 o4 = {v0, v1, v2, v3};
                *(float4*)&Cf[(size_t)row * NC + c0] = o4;
            } else if (vtile) {
                // V tile: store transposed to Vt[(bh*64+d)*2048 + s]
                int d = c0 - 1536;            // 0..767 across heads
                int bq_ = row >> 11;          // batch
                int s = row & 2047;
                int h = d >> 6, dd = d & 63;
                size_t base = ((size_t)(bq_ * 12 + h) * 64 + dd) * 2048 + s;
                Vt[base]          = f2bf_bits(v0);
                Vt[base + 2048]   = f2bf_bits(v1);
                Vt[base + 4096]   = f2bf_bits(v2);
                Vt[base + 6144]   = f2bf_bits(v3);
            } else {
                uint2 pk = {pack2bf(v0, v1), pack2bf(v2, v3)};
                *(uint2*)&Cb[(size_t)row * NC + c0] = pk;
            }
        }
    }
}

// ---- flash attention, S^T formulation, fixed-max softmax -----------------
// v5: 1536 single-q-tile blocks (64 rows), dispatched LARGEST-FIRST (qt
//     descending with bx) -> LPT backfill kills the tail that capped v4
//     (per-block iters 17..32 with all blocks resident = longest sets wall;
//     measured occupancy 26% ~= avg/max iters * static). LDS slashed to
//     25.6KB (Q frags direct from global; K/V single 8KB buffers) -> 5-6
//     blocks/CU. 2-barrier phase-rotated staging: K(kt+1) DMA overlaps PV,
//     V(kt+1) DMA overlaps next QK; per-wave vmcnt drain at each barrier
//     makes the single-buffer overwrite race-free.

__global__ __launch_bounds__(256, 5) void attn_kernel(
    const u16* __restrict__ QKV, const u16* __restrict__ Vt, u16* __restrict__ O) {
    __shared__ u16 lsK[64 * 64];       // 8KB
    __shared__ u16 lsV[64 * 64];       // 8KB
    __shared__ u16 lsP[4][16 * 72];    // 9KB, wave-private P staging

    int bx = blockIdx.x;               // 1536 = 32 qt (descending) x 48 bh
    int bh = bx % 48;                  // 48 % 8 == 0: same-bh blocks share XCD
    int qt = 31 - bx / 48;             // big tiles dispatched first (LPT)
    int bb = bh / 12, h = bh % 12;
    int tid = threadIdx.x, w = tid >> 6, lane = tid & 63;
    int quad = lane >> 4, l15 = lane & 15;
    int rr = lane >> 3, c8 = lane & 7;

    const size_t kgbase = (size_t)(bb * 2048) * 2304 + 768 + (size_t)h * 64;
    const size_t vgbase = (size_t)(bh * 64) * 2048;

    auto stageK = [&](int kt) {
        for (int cb = w; cb < 8; cb += 4) {
            int row = cb * 8 + rr;
            int cg = c8 ^ ((rr ^ cb) & 7);
            gld_lds16(QKV + kgbase + (size_t)(kt * 64 + row) * 2304 + cg * 8,
                      &lsK[cb * 512]);
        }
    };
    auto stageV = [&](int kt) {
        for (int cb = w; cb < 8; cb += 4) {
            int row = cb * 8 + rr;
            int cg = c8 ^ ((rr ^ cb) & 7);
            gld_lds16(Vt + vgbase + (size_t)row * 2048 + kt * 64 + cg * 8,
                      &lsV[cb * 512]);
        }
    };

    // Q fragments straight from global: lane (quad,l15) needs k-chunks quad
    // and 4+quad of its q-row -> two 16B loads, no LDS round-trip.
    const int qrow = qt * 64 + w * 16 + l15;
    const u16* qp = QKV + (size_t)(bb * 2048 + qrow) * 2304 + (size_t)h * 64;
    bf16x8 q0 = *(const bf16x8*)(qp + quad * 8);
    bf16x8 q1 = *(const bf16x8*)(qp + 32 + quad * 8);

    stageK(0);
    stageV(0);
    __syncthreads();

    f32x4 oacc[4];
    for (int dt = 0; dt < 4; ++dt) oacc[dt] = (f32x4){0.f, 0.f, 0.f, 0.f};
    float li = 0.f;
    u16* Pw = lsP[w];
    const int qrel = w * 16 + l15;

    for (int kt = 0; kt <= qt; ++kt) {
        // ---- QK^T (K(kt) guaranteed resident by previous barrier) ----
        f32x4 S[4];
        __builtin_amdgcn_s_setprio(1);
        for (int ct = 0; ct < 4; ++ct) {
            int rowk = ct * 16 + l15;
            int swk = (rowk ^ (rowk >> 3)) & 7;
            bf16x8 k0 = *(const bf16x8*)&lsK[rowk * 64 + ((0 + quad) ^ swk) * 8];
            bf16x8 k1 = *(const bf16x8*)&lsK[rowk * 64 + ((4 + quad) ^ swk) * 8];
            f32x4 z = (f32x4){0.f, 0.f, 0.f, 0.f};
            S[ct] = __builtin_amdgcn_mfma_f32_16x16x32_bf16(k0, q0, z, 0, 0, 0);
            S[ct] = __builtin_amdgcn_mfma_f32_16x16x32_bf16(k1, q1, S[ct], 0, 0, 0);
        }
        __builtin_amdgcn_s_setprio(0);

        if (kt == qt) {                 // diagonal tile: causal mask
            for (int ct = 0; ct < 4; ++ct) {
                int kbase = ct * 16 + quad * 4;
                for (int r = 0; r < 4; ++r)
                    if (kbase + r > qrel) S[ct][r] = -1e30f;
            }
        }

        // ---- softmax -> P (wave-private LDS, lgkm-ordered) ----
        {
            u16* Pr = &Pw[(size_t)l15 * 72];
            for (int ct = 0; ct < 4; ++ct) {
                float p0 = __builtin_amdgcn_exp2f(S[ct][0] * CEXP);
                float p1 = __builtin_amdgcn_exp2f(S[ct][1] * CEXP);
                float p2 = __builtin_amdgcn_exp2f(S[ct][2] * CEXP);
                float p3 = __builtin_amdgcn_exp2f(S[ct][3] * CEXP);
                li += (p0 + p1) + (p2 + p3);
                uint2 pk = {pack2bf(p0, p1), pack2bf(p2, p3)};
                *(uint2*)&Pr[ct * 16 + quad * 4] = pk;
            }
        }

        __syncthreads();   // A: drains V(kt) DMA; all lsK(kt) reads done
        if (kt < qt) stageK(kt + 1);    // K DMA overlaps PV below

        // ---- PV ----
        __builtin_amdgcn_s_setprio(1);
        for (int ks = 0; ks < 2; ++ks) {
            bf16x8 bp = *(const bf16x8*)&Pw[(size_t)l15 * 72 + ks * 32 + quad * 8];
            for (int dt = 0; dt < 4; ++dt) {
                int rowv = dt * 16 + l15;
                int swv = (rowv ^ (rowv >> 3)) & 7;
                bf16x8 av = *(const bf16x8*)&lsV[rowv * 64 + ((ks * 4 + quad) ^ swv) * 8];
                oacc[dt] = __builtin_amdgcn_mfma_f32_16x16x32_bf16(av, bp, oacc[dt], 0, 0, 0);
            }
        }
        __builtin_amdgcn_s_setprio(0);

        __syncthreads();   // B: drains K(kt+1) DMA; all lsV(kt) reads done
        if (kt < qt) stageV(kt + 1);    // V DMA overlaps next QK^T
    }

    li += __shfl_xor(li, 16, 64);
    li += __shfl_xor(li, 32, 64);
    float inv = 1.0f / li;

    for (int dt = 0; dt < 4; ++dt) {
        uint2 pk = {pack2bf(oacc[dt][0] * inv, oacc[dt][1] * inv),
                    pack2bf(oacc[dt][2] * inv, oacc[dt][3] * inv)};
        *(uint2*)&O[(size_t)(bb * 2048 + qrow) * 768 + h * 64 + dt * 16 + quad * 4] = pk;
    }
}

// ---- launch --------------------------------------------------------------

extern "C" void kernel_launch(void* const* d_in, const int* in_sizes, int n_in,
                              void* d_out, int out_size, void* d_ws, size_t ws_size,
                              hipStream_t stream) {
    const float* x  = (const float*)d_in[0];
    const float* wq = (const float*)d_in[1];
    const float* bq = (const float*)d_in[2];
    const float* wk = (const float*)d_in[3];
    const float* bk = (const float*)d_in[4];
    const float* wv = (const float*)d_in[5];
    const float* bv = (const float*)d_in[6];
    const float* wo = (const float*)d_in[7];
    const float* bo = (const float*)d_in[8];
    float* out = (float*)d_out;

    char* ws = (char*)d_ws;
    u16*   xb    = (u16*)(ws + 0);            // 8192x768 bf16
    u16*   Wf    = (u16*)(ws + 12582912);     // 2304x768 bf16
    u16*   wob   = (u16*)(ws + 16121856);     //  768x768 bf16
    float* biasf = (float*)(ws + 17301504);   // 2304 f32
    u16*   QKVb  = (u16*)(ws + 17310720);     // 8192x2304 bf16 (V region unused)
    u16*   Vtw   = (u16*)(ws + 55059456);     // 48x64x2048 bf16
    u16*   Ow    = (u16*)(ws + 67642368);     // 8192x768 bf16

    cast_all_kernel<<<8448, 256, 0, stream>>>(x, wq, wk, wv, wo,
                                              xb, Wf, Wf + 589824, Wf + 1179648, wob,
                                              bq, bk, bv, biasf);

    // fused QKV projection (V tiles stored transposed into Vtw)
    gemm_xwt<128, 2><<<dim3(18, 64), 256, 0, stream>>>(xb, Wf, biasf, nullptr, QKVb,
                                                       Vtw, 768, 2304);
    attn_kernel<<<1536, 256, 0, stream>>>(QKVb, Vtw, Ow);
    // output projection -> fp32 d_out
    gemm_xwt<64, 1><<<dim3(6, 128), 256, 0, stream>>>(Ow, wob, bo, out, nullptr,
                                                      nullptr, 768, 768);
}